// Round 8
// baseline (187.384 us; speedup 1.0000x reference)
//
#include <hip/hip_runtime.h>

// Mamba2D: B=4, C=128, H=W=64 (L=4096), D_INNER=256, D_STATE=16, DT_RANK=8, D_CONV=4
//  prep:      W2b=bf16(in_proj@proj); wTb48=bf16 pad48(x_proj_w); Woutb=bf16(out_proj_w); Aneg
//  gemm_xz:   bf16 MFMA -> xzb (bf16, 16 MB)
//  conv_silu: xcb = bf16 silu(conv4(xzb[:, :256]) + b)
//  xdbl_mfma: xdbl48[m][48] = xcb @ wTb48^T (cols 0..7 dt_r, 8..23 B, 24..39 C)
//  scan:      3-phase, CLEN=16, NCHUNK=256; scan1/scan3 process TWO chunks per
//             block interleaved in registers (32 independent chains -> 2x ILP);
//             chunk states bf16
//  gemm_out:  bf16 MFMA, out = Wout @ y2 + x

#define NCHUNK 256
#define CLEN 16

using s16x8 = __attribute__((ext_vector_type(8))) short;
using f32x4 = __attribute__((ext_vector_type(4))) float;

__device__ inline unsigned short f2bf(float f) {
  unsigned u = __float_as_uint(f);
  u = u + 0x7FFF + ((u >> 16) & 1);
  return (unsigned short)(u >> 16);
}
__device__ inline float bfu(unsigned short v) {
  return __uint_as_float((unsigned)v << 16);
}
__device__ inline float bf2f_lo(unsigned v) { return __uint_as_float(v << 16); }
__device__ inline float bf2f_hi(unsigned v) { return __uint_as_float(v & 0xFFFF0000u); }

// ---------------- prep ----------------
__global__ void prep_kernel(const float* __restrict__ proj_w,
                            const float* __restrict__ in_proj_w,
                            const float* __restrict__ x_proj_w,
                            const float* __restrict__ out_proj_w,
                            const float* __restrict__ A_log,
                            unsigned short* __restrict__ W2b,
                            unsigned short* __restrict__ wTb48,
                            unsigned short* __restrict__ Woutb,
                            float* __restrict__ Aneg) {
  int idx = blockIdx.x * blockDim.x + threadIdx.x;
  if (idx < 65536) {
    int o = idx >> 7, c = idx & 127;
    float acc = 0.f;
    #pragma unroll 4
    for (int i = 0; i < 128; ++i)
      acc += in_proj_w[o * 128 + i] * proj_w[i * 128 + c];
    W2b[idx] = f2bf(acc);
  } else if (idx < 65536 + 12288) {
    int t = idx - 65536;
    int j = t >> 8, k = t & 255;
    wTb48[t] = (j < 40) ? f2bf(x_proj_w[j * 256 + k]) : (unsigned short)0;
  } else if (idx < 65536 + 12288 + 32768) {
    int t = idx - (65536 + 12288);
    Woutb[t] = f2bf(out_proj_w[t]);
  } else if (idx < 65536 + 12288 + 32768 + 4096) {
    int t = idx - (65536 + 12288 + 32768);
    Aneg[t] = -__expf(A_log[t]);
  }
}

// ---------------- xz GEMM via bf16 MFMA -> bf16 out ----------------
__global__ __launch_bounds__(256, 1) void gemm_xz_kernel(
    const float* __restrict__ x, const unsigned short* __restrict__ W2b,
    unsigned short* __restrict__ xzb) {
  __shared__ __align__(16) unsigned short At[128 * 128];
  __shared__ __align__(16) unsigned short Bt[256 * 128];
  int m0 = (blockIdx.x >> 1) * 128;
  int o0 = (blockIdx.x & 1) * 256;
  int b  = m0 >> 12;
  int l0 = m0 & 4095;
  int t = threadIdx.x;
  #pragma unroll
  for (int j = 0; j < 16; ++j) {
    int flat = t + j * 256;
    int cr = flat >> 5, lq = (flat & 31) << 2;
    float4 v = *reinterpret_cast<const float4*>(
        &x[((size_t)(b * 128 + cr)) * 4096 + l0 + lq]);
    float vv[4] = {v.x, v.y, v.z, v.w};
    #pragma unroll
    for (int e = 0; e < 4; ++e) {
      int l = lq + e;
      int g = (cr >> 3) ^ ((l & 7) << 1);
      At[l * 128 + g * 8 + (cr & 7)] = f2bf(vv[e]);
    }
  }
  #pragma unroll
  for (int j = 0; j < 16; ++j) {
    int flat = t + j * 256;
    int row = flat >> 4, gB = flat & 15;
    s16x8 v = *reinterpret_cast<const s16x8*>(&W2b[(size_t)(o0 + row) * 128 + gB * 8]);
    int g = gB ^ ((row & 7) << 1);
    *reinterpret_cast<s16x8*>(&Bt[row * 128 + g * 8]) = v;
  }
  __syncthreads();
  int ln = t & 63, wave = t >> 6;
  int wm = wave & 1, wn = wave >> 1;
  f32x4 acc[4][8] = {};
  #pragma unroll
  for (int ks = 0; ks < 4; ++ks) {
    int gk = ks * 4 + (ln >> 4);
    s16x8 a[4], bb[8];
    #pragma unroll
    for (int mi = 0; mi < 4; ++mi) {
      int lr = wm * 64 + mi * 16 + (ln & 15);
      a[mi] = *reinterpret_cast<const s16x8*>(&At[lr * 128 + (gk ^ ((lr & 7) << 1)) * 8]);
    }
    #pragma unroll
    for (int ni = 0; ni < 8; ++ni) {
      int orow = wn * 128 + ni * 16 + (ln & 15);
      bb[ni] = *reinterpret_cast<const s16x8*>(&Bt[orow * 128 + (gk ^ ((orow & 7) << 1)) * 8]);
    }
    #pragma unroll
    for (int mi = 0; mi < 4; ++mi)
      #pragma unroll
      for (int ni = 0; ni < 8; ++ni)
        acc[mi][ni] = __builtin_amdgcn_mfma_f32_16x16x32_bf16(a[mi], bb[ni], acc[mi][ni], 0, 0, 0);
  }
  #pragma unroll
  for (int mi = 0; mi < 4; ++mi)
    #pragma unroll
    for (int ni = 0; ni < 8; ++ni)
      #pragma unroll
      for (int r = 0; r < 4; ++r) {
        int row = wm * 64 + mi * 16 + (ln >> 4) * 4 + r;
        int col = wn * 128 + ni * 16 + (ln & 15);
        xzb[(size_t)(m0 + row) * 512 + o0 + col] = f2bf(acc[mi][ni][r]);
      }
}

// ---------------- causal depthwise conv4 + silu (bf16 in/out) ----------------
__global__ __launch_bounds__(256) void conv_silu_kernel(
    const unsigned short* __restrict__ xzb, const float* __restrict__ conv_w,
    const float* __restrict__ conv_b, unsigned short* __restrict__ xcb) {
  int bl0 = blockIdx.x * 8;
  int d = threadIdx.x;
  int l0 = bl0 & 4095;
  float w0 = conv_w[d * 4 + 0], w1 = conv_w[d * 4 + 1];
  float w2 = conv_w[d * 4 + 2], w3 = conv_w[d * 4 + 3];
  float cb = conv_b[d];
  float xm1 = (l0 >= 1) ? bfu(xzb[(size_t)(bl0 - 1) * 512 + d]) : 0.f;
  float xm2 = (l0 >= 2) ? bfu(xzb[(size_t)(bl0 - 2) * 512 + d]) : 0.f;
  float xm3 = (l0 >= 3) ? bfu(xzb[(size_t)(bl0 - 3) * 512 + d]) : 0.f;
  #pragma unroll
  for (int r = 0; r < 8; ++r) {
    size_t bl = bl0 + r;
    float x0 = bfu(xzb[bl * 512 + d]);
    float acc = cb + w3 * x0 + w2 * xm1 + w1 * xm2 + w0 * xm3;
    float s = acc * (1.f / (1.f + __expf(-acc)));
    xcb[bl * 256 + d] = f2bf(s);
    xm3 = xm2; xm2 = xm1; xm1 = x0;
  }
}

// ---------------- x_dbl via bf16 MFMA: [16384 x 48] = xcb @ wTb48^T ----------------
__global__ __launch_bounds__(256) void xdbl_mfma_kernel(
    const unsigned short* __restrict__ xcb, const unsigned short* __restrict__ wTb48,
    float* __restrict__ xdbl48) {
  __shared__ __align__(16) unsigned short At[64 * 256];
  __shared__ __align__(16) unsigned short Bt[48 * 256];
  int m0 = blockIdx.x * 64;
  int t = threadIdx.x;
  #pragma unroll
  for (int it = 0; it < 8; ++it) {
    int f = t + it * 256;
    int row = f >> 5, g0 = f & 31;
    s16x8 v = *reinterpret_cast<const s16x8*>(&xcb[(size_t)(m0 + row) * 256 + g0 * 8]);
    int g = g0 ^ ((row & 7) << 1);
    *reinterpret_cast<s16x8*>(&At[row * 256 + g * 8]) = v;
  }
  #pragma unroll
  for (int it = 0; it < 6; ++it) {
    int f = t + it * 256;
    int row = f >> 5, g0 = f & 31;
    s16x8 v = *reinterpret_cast<const s16x8*>(&wTb48[(size_t)row * 256 + g0 * 8]);
    int g = g0 ^ ((row & 7) << 1);
    *reinterpret_cast<s16x8*>(&Bt[row * 256 + g * 8]) = v;
  }
  __syncthreads();
  int ln = t & 63, wm = t >> 6;
  f32x4 acc[3] = {};
  #pragma unroll
  for (int ks = 0; ks < 8; ++ks) {
    int gk = ks * 4 + (ln >> 4);
    int ar = wm * 16 + (ln & 15);
    s16x8 a = *reinterpret_cast<const s16x8*>(&At[ar * 256 + (gk ^ ((ar & 7) << 1)) * 8]);
    #pragma unroll
    for (int nt = 0; nt < 3; ++nt) {
      int br = nt * 16 + (ln & 15);
      s16x8 bb = *reinterpret_cast<const s16x8*>(&Bt[br * 256 + (gk ^ ((br & 7) << 1)) * 8]);
      acc[nt] = __builtin_amdgcn_mfma_f32_16x16x32_bf16(a, bb, acc[nt], 0, 0, 0);
    }
  }
  #pragma unroll
  for (int nt = 0; nt < 3; ++nt)
    #pragma unroll
    for (int r = 0; r < 4; ++r) {
      int row = m0 + wm * 16 + (ln >> 4) * 4 + r;
      xdbl48[(size_t)row * 48 + nt * 16 + (ln & 15)] = acc[nt][r];
    }
}

// ---------------- scan phase 1: TWO chunks/block, 32 interleaved chains ----------------
__global__ __launch_bounds__(256) void scan1_kernel(
    const unsigned short* __restrict__ xcb, const float* __restrict__ xdbl48,
    const float* __restrict__ dt_proj_w, const float* __restrict__ dt_proj_b,
    const float* __restrict__ Aneg,
    float* __restrict__ Ssum, unsigned* __restrict__ chHb) {
  __shared__ __align__(16) float lBC[32][32];
  __shared__ __align__(16) float sdtr[32][8];
  int blk = blockIdx.x;            // b*128 + cp  (cp = chunk pair)
  int b = blk >> 7, cp = blk & 127;
  int bl0 = blk * 32;              // 32 consecutive rows = chunks 2cp, 2cp+1
  int tid = threadIdx.x;
  {
    int t0 = tid >> 3, q = (tid & 7) << 2;
    *reinterpret_cast<float4*>(&lBC[t0][q]) =
        *reinterpret_cast<const float4*>(&xdbl48[(size_t)(bl0 + t0) * 48 + 8 + q]);
  }
  if (tid < 64) {
    int t1 = tid >> 1, q1 = (tid & 1) << 2;
    *reinterpret_cast<float4*>(&sdtr[t1][q1]) =
        *reinterpret_cast<const float4*>(&xdbl48[(size_t)(bl0 + t1) * 48 + q1]);
  }
  int d = tid;
  float wrow[8];
  *reinterpret_cast<float4*>(&wrow[0]) =
      *reinterpret_cast<const float4*>(&dt_proj_w[d * 8]);
  *reinterpret_cast<float4*>(&wrow[4]) =
      *reinterpret_cast<const float4*>(&dt_proj_w[d * 8 + 4]);
  float bb = dt_proj_b[d];
  float An[16];
  #pragma unroll
  for (int q = 0; q < 4; ++q)
    *reinterpret_cast<float4*>(&An[q * 4]) =
        *reinterpret_cast<const float4*>(&Aneg[d * 16 + q * 4]);
  unsigned xp[CLEN];               // packed bf16: lo=chunkA row t, hi=chunkB row 16+t
  #pragma unroll
  for (int t = 0; t < CLEN; ++t) {
    unsigned lo = xcb[(size_t)(bl0 + t) * 256 + d];
    unsigned hi = xcb[(size_t)(bl0 + 16 + t) * 256 + d];
    xp[t] = lo | (hi << 16);
  }
  __syncthreads();
  float hA[16] = {}, hB[16] = {};
  float SA = 0.f, SB = 0.f;
  #pragma unroll
  for (int t = 0; t < CLEN; ++t) {
    float aA = bb, aB = bb;
    #pragma unroll
    for (int q = 0; q < 8; ++q) {
      aA += sdtr[t][q] * wrow[q];
      aB += sdtr[16 + t][q] * wrow[q];
    }
    float dlA = fmaxf(aA, 0.f) + __logf(1.f + __expf(-fabsf(aA)));
    float dlB = fmaxf(aB, 0.f) + __logf(1.f + __expf(-fabsf(aB)));
    SA += dlA; SB += dlB;
    float dlxA = dlA * bf2f_lo(xp[t]);
    float dlxB = dlB * bf2f_hi(xp[t]);
    #pragma unroll
    for (int n = 0; n < 16; ++n) {
      hA[n] = __expf(dlA * An[n]) * hA[n] + dlxA * lBC[t][n];
      hB[n] = __expf(dlB * An[n]) * hB[n] + dlxB * lBC[16 + t][n];
    }
  }
  int p = b * 256 + d;
  int c0 = cp * 2;
  Ssum[c0 * 1024 + p] = SA;
  Ssum[(c0 + 1) * 1024 + p] = SB;
  unsigned upA[8], upB[8];
  #pragma unroll
  for (int q = 0; q < 8; ++q) {
    upA[q] = (unsigned)f2bf(hA[2 * q]) | ((unsigned)f2bf(hA[2 * q + 1]) << 16);
    upB[q] = (unsigned)f2bf(hB[2 * q]) | ((unsigned)f2bf(hB[2 * q + 1]) << 16);
  }
  size_t ubA = ((size_t)(c0 * 1024 + p)) * 8;
  size_t ubB = ((size_t)((c0 + 1) * 1024 + p)) * 8;
  *reinterpret_cast<uint4*>(&chHb[ubA])     = uint4{upA[0], upA[1], upA[2], upA[3]};
  *reinterpret_cast<uint4*>(&chHb[ubA + 4]) = uint4{upA[4], upA[5], upA[6], upA[7]};
  *reinterpret_cast<uint4*>(&chHb[ubB])     = uint4{upB[0], upB[1], upB[2], upB[3]};
  *reinterpret_cast<uint4*>(&chHb[ubB + 4]) = uint4{upB[4], upB[5], upB[6], upB[7]};
}

// ---------------- scan phase 2: chunk prefix over 256 chunks (bf16 states) ----------------
__global__ void scan2_kernel(const float* __restrict__ Aneg,
                             const float* __restrict__ Ssum,
                             const unsigned short* __restrict__ chHb,
                             unsigned short* __restrict__ chSb) {
  int q = blockIdx.x * blockDim.x + threadIdx.x;  // 0..16383
  int p = q >> 4, n = q & 15;
  int d = p & 255;
  float An = Aneg[d * 16 + n];
  float h = 0.f;
  #pragma unroll 8
  for (int c = 0; c < NCHUNK; ++c) {
    size_t idx = ((size_t)(c * 1024 + p)) * 16 + n;
    float S = Ssum[c * 1024 + p];
    float hl = bf2f_lo((unsigned)chHb[idx]);
    chSb[idx] = f2bf(h);
    h = __expf(An * S) * h + hl;
  }
}

// ---------------- scan phase 3: TWO chunks/block, replay + y + epilogue ----------------
__global__ __launch_bounds__(256) void scan3_kernel(
    const unsigned short* __restrict__ xcb, const float* __restrict__ xdbl48,
    const float* __restrict__ dt_proj_w, const float* __restrict__ dt_proj_b,
    const float* __restrict__ Aneg, const unsigned* __restrict__ chSb,
    const float* __restrict__ Dvec, const unsigned short* __restrict__ xzb,
    unsigned short* __restrict__ y2b) {
  __shared__ __align__(16) float lBC[32][32];
  __shared__ __align__(16) float sdtr[32][8];
  int blk = blockIdx.x;
  int b = blk >> 7, cp = blk & 127;
  int bl0 = blk * 32;
  int tid = threadIdx.x;
  {
    int t0 = tid >> 3, q = (tid & 7) << 2;
    *reinterpret_cast<float4*>(&lBC[t0][q]) =
        *reinterpret_cast<const float4*>(&xdbl48[(size_t)(bl0 + t0) * 48 + 8 + q]);
  }
  if (tid < 64) {
    int t1 = tid >> 1, q1 = (tid & 1) << 2;
    *reinterpret_cast<float4*>(&sdtr[t1][q1]) =
        *reinterpret_cast<const float4*>(&xdbl48[(size_t)(bl0 + t1) * 48 + q1]);
  }
  int d = tid;
  float wrow[8];
  *reinterpret_cast<float4*>(&wrow[0]) =
      *reinterpret_cast<const float4*>(&dt_proj_w[d * 8]);
  *reinterpret_cast<float4*>(&wrow[4]) =
      *reinterpret_cast<const float4*>(&dt_proj_w[d * 8 + 4]);
  float bb = dt_proj_b[d];
  float An[16];
  #pragma unroll
  for (int q = 0; q < 4; ++q)
    *reinterpret_cast<float4*>(&An[q * 4]) =
        *reinterpret_cast<const float4*>(&Aneg[d * 16 + q * 4]);
  int p = b * 256 + d;
  int c0 = cp * 2;
  float hA[16], hB[16];
  {
    size_t ubA = ((size_t)(c0 * 1024 + p)) * 8;
    size_t ubB = ((size_t)((c0 + 1) * 1024 + p)) * 8;
    #pragma unroll
    for (int q = 0; q < 8; ++q) {
      unsigned vA = chSb[ubA + q];
      unsigned vB = chSb[ubB + q];
      hA[2 * q] = bf2f_lo(vA); hA[2 * q + 1] = bf2f_hi(vA);
      hB[2 * q] = bf2f_lo(vB); hB[2 * q + 1] = bf2f_hi(vB);
    }
  }
  unsigned xp[CLEN], zp[CLEN];
  #pragma unroll
  for (int t = 0; t < CLEN; ++t) {
    unsigned xlo = xcb[(size_t)(bl0 + t) * 256 + d];
    unsigned xhi = xcb[(size_t)(bl0 + 16 + t) * 256 + d];
    xp[t] = xlo | (xhi << 16);
    unsigned zlo = xzb[(size_t)(bl0 + t) * 512 + 256 + d];
    unsigned zhi = xzb[(size_t)(bl0 + 16 + t) * 512 + 256 + d];
    zp[t] = zlo | (zhi << 16);
  }
  float Dd = Dvec[d];
  __syncthreads();
  #pragma unroll
  for (int t = 0; t < CLEN; ++t) {
    float aA = bb, aB = bb;
    #pragma unroll
    for (int q = 0; q < 8; ++q) {
      aA += sdtr[t][q] * wrow[q];
      aB += sdtr[16 + t][q] * wrow[q];
    }
    float dlA = fmaxf(aA, 0.f) + __logf(1.f + __expf(-fabsf(aA)));
    float dlB = fmaxf(aB, 0.f) + __logf(1.f + __expf(-fabsf(aB)));
    float xA = bf2f_lo(xp[t]), xB = bf2f_hi(xp[t]);
    float dlxA = dlA * xA, dlxB = dlB * xB;
    float yA = 0.f, yB = 0.f;
    #pragma unroll
    for (int n = 0; n < 16; ++n) {
      hA[n] = __expf(dlA * An[n]) * hA[n] + dlxA * lBC[t][n];
      hB[n] = __expf(dlB * An[n]) * hB[n] + dlxB * lBC[16 + t][n];
      yA += hA[n] * lBC[t][16 + n];
      yB += hB[n] * lBC[16 + t][16 + n];
    }
    float zA = bf2f_lo(zp[t]), zB = bf2f_hi(zp[t]);
    float silA = zA * (1.f / (1.f + __expf(-zA)));
    float silB = zB * (1.f / (1.f + __expf(-zB)));
    y2b[(size_t)(bl0 + t) * 256 + d] = f2bf((yA + xA * Dd) * silA);
    y2b[(size_t)(bl0 + 16 + t) * 256 + d] = f2bf((yB + xB * Dd) * silB);
  }
}

// ---------------- out GEMM via bf16 MFMA: out = Wout @ y2 + x ----------------
__global__ __launch_bounds__(256) void gemm_out_kernel(
    const unsigned short* __restrict__ y2b, const unsigned short* __restrict__ Woutb,
    const float* __restrict__ x, float* __restrict__ out) {
  __shared__ __align__(16) unsigned short At[64 * 256];
  __shared__ __align__(16) unsigned short Bt[128 * 256];
  int m0 = blockIdx.x * 64;
  int b = m0 >> 12, l0 = m0 & 4095;
  int t = threadIdx.x;
  #pragma unroll
  for (int it = 0; it < 8; ++it) {
    int f = t + it * 256;
    int row = f >> 5, g0 = f & 31;
    s16x8 v = *reinterpret_cast<const s16x8*>(&y2b[(size_t)(m0 + row) * 256 + g0 * 8]);
    int g = g0 ^ ((row & 7) << 1);
    *reinterpret_cast<s16x8*>(&At[row * 256 + g * 8]) = v;
  }
  #pragma unroll
  for (int it = 0; it < 16; ++it) {
    int f = t + it * 256;
    int row = f >> 5, g0 = f & 31;
    s16x8 v = *reinterpret_cast<const s16x8*>(&Woutb[(size_t)row * 256 + g0 * 8]);
    int g = g0 ^ ((row & 7) << 1);
    *reinterpret_cast<s16x8*>(&Bt[row * 256 + g * 8]) = v;
  }
  __syncthreads();
  int ln = t & 63, wm = t >> 6;
  f32x4 acc[8] = {};
  #pragma unroll
  for (int ks = 0; ks < 8; ++ks) {
    int gk = ks * 4 + (ln >> 4);
    int ar = wm * 16 + (ln & 15);
    s16x8 a = *reinterpret_cast<const s16x8*>(&At[ar * 256 + (gk ^ ((ar & 7) << 1)) * 8]);
    #pragma unroll
    for (int nt = 0; nt < 8; ++nt) {
      int br = nt * 16 + (ln & 15);
      s16x8 bb = *reinterpret_cast<const s16x8*>(&Bt[br * 256 + (gk ^ ((br & 7) << 1)) * 8]);
      acc[nt] = __builtin_amdgcn_mfma_f32_16x16x32_bf16(a, bb, acc[nt], 0, 0, 0);
    }
  }
  #pragma unroll
  for (int nt = 0; nt < 8; ++nt) {
    int cc = nt * 16 + (ln & 15);
    size_t base = ((size_t)(b * 128 + cc)) * 4096 + l0 + wm * 16 + ((ln >> 4) << 2);
    float4 xr = *reinterpret_cast<const float4*>(&x[base]);
    float4 o{acc[nt][0] + xr.x, acc[nt][1] + xr.y, acc[nt][2] + xr.z, acc[nt][3] + xr.w};
    *reinterpret_cast<float4*>(&out[base]) = o;
  }
}

extern "C" void kernel_launch(void* const* d_in, const int* in_sizes, int n_in,
                              void* d_out, int out_size, void* d_ws, size_t ws_size,
                              hipStream_t stream) {
  const float* x         = (const float*)d_in[0];
  const float* proj_w    = (const float*)d_in[1];
  const float* in_proj_w = (const float*)d_in[2];
  const float* conv_w    = (const float*)d_in[3];
  const float* conv_b    = (const float*)d_in[4];
  const float* x_proj_w  = (const float*)d_in[5];
  const float* dt_proj_w = (const float*)d_in[6];
  const float* dt_proj_b = (const float*)d_in[7];
  const float* A_log     = (const float*)d_in[8];
  const float* Dvec      = (const float*)d_in[9];
  const float* out_proj_w= (const float*)d_in[10];

  float* ws = (float*)d_ws;
  float*          Aneg   = ws;                                  // 4096 f
  unsigned short* W2b    = (unsigned short*)(ws + 4096);        // 65536 u16
  unsigned short* wTb48  = (unsigned short*)(ws + 36864);       // 12288 u16
  unsigned short* Woutb  = (unsigned short*)(ws + 43008);       // 32768 u16
  unsigned short* xzb    = (unsigned short*)(ws + 59392);       // 8388608 u16 (16 MB)
  unsigned short* xcb    = (unsigned short*)(ws + 4253696);     // 4194304 u16 (8 MB)
  float*          xdbl48 = ws + 6350848;                        // 786432 f (3 MB)
  float*          Ssum   = ws + 7137280;                        // 262144 f (1 MB)
  unsigned*       chHb   = (unsigned*)(ws + 7399424);           // 2097152 u32 (8 MB)
  unsigned*       chSb   = (unsigned*)(ws + 9496576);           // 2097152 u32 (8 MB)
  unsigned short* y2b    = (unsigned short*)(ws + 11593728);    // 4194304 u16 (8 MB)
  float* out = (float*)d_out;                                   // total ~52 MB

  prep_kernel<<<448, 256, 0, stream>>>(proj_w, in_proj_w, x_proj_w, out_proj_w, A_log,
                                       W2b, wTb48, Woutb, Aneg);
  gemm_xz_kernel<<<256, 256, 0, stream>>>(x, W2b, xzb);
  conv_silu_kernel<<<2048, 256, 0, stream>>>(xzb, conv_w, conv_b, xcb);
  xdbl_mfma_kernel<<<256, 256, 0, stream>>>(xcb, wTb48, xdbl48);
  scan1_kernel<<<512, 256, 0, stream>>>(xcb, xdbl48, dt_proj_w, dt_proj_b, Aneg,
                                        Ssum, chHb);
  scan2_kernel<<<64, 256, 0, stream>>>(Aneg, Ssum, (const unsigned short*)chHb,
                                       (unsigned short*)chSb);
  scan3_kernel<<<512, 256, 0, stream>>>(xcb, xdbl48, dt_proj_w, dt_proj_b, Aneg,
                                        chSb, Dvec, xzb, y2b);
  gemm_out_kernel<<<256, 256, 0, stream>>>(y2b, Woutb, x, out);
}

// Round 9
// 184.102 us; speedup vs baseline: 1.0178x; 1.0178x over previous
//
#include <hip/hip_runtime.h>

// Mamba2D: B=4, C=128, H=W=64 (L=4096), D_INNER=256, D_STATE=16, DT_RANK=8, D_CONV=4
// Layout strategy this round: scan-side tensors are d-major ("T" = [b][d][l]) so the
// scan reads/writes are contiguous 16B per thread (G13); GEMM-side tensors stay l-major.
//  prep:      W2b=bf16(in_proj@proj); wTb48; Woutb; Aneg
//  gemm_xz:   bf16 MFMA; writes xT (x-half) and zT (z-half) d-major via ushort4
//  conv:      thread=(d,16 l): vector window reads from xT, writes xcT (d-major)
//             + LDS-transposed xcb (l-major, for x_dbl MFMA)
//  xdbl_mfma: xdbl48[l][48] = xcb @ wTb48^T
//  scan1:     per-chunk (CLEN=32): delta in-reg, h[16] fp32 -> Ssum, chH (fp32)
//  scan2:     chunk prefix (fp32, restrict)
//  scan3:     replay + y; y routed through LDS transpose -> l-major bf16 y2b
//  gemm_out:  bf16 MFMA, out = Wout @ y2 + x

#define NCHUNK 128
#define CLEN 32

using s16x8 = __attribute__((ext_vector_type(8))) short;
using f32x4 = __attribute__((ext_vector_type(4))) float;

__device__ inline unsigned short f2bf(float f) {
  unsigned u = __float_as_uint(f);
  u = u + 0x7FFF + ((u >> 16) & 1);
  return (unsigned short)(u >> 16);
}
__device__ inline float bfu(unsigned short v) {
  return __uint_as_float((unsigned)v << 16);
}

// ---------------- prep ----------------
__global__ void prep_kernel(const float* __restrict__ proj_w,
                            const float* __restrict__ in_proj_w,
                            const float* __restrict__ x_proj_w,
                            const float* __restrict__ out_proj_w,
                            const float* __restrict__ A_log,
                            unsigned short* __restrict__ W2b,
                            unsigned short* __restrict__ wTb48,
                            unsigned short* __restrict__ Woutb,
                            float* __restrict__ Aneg) {
  int idx = blockIdx.x * blockDim.x + threadIdx.x;
  if (idx < 65536) {
    int o = idx >> 7, c = idx & 127;
    float acc = 0.f;
    #pragma unroll 4
    for (int i = 0; i < 128; ++i)
      acc += in_proj_w[o * 128 + i] * proj_w[i * 128 + c];
    W2b[idx] = f2bf(acc);
  } else if (idx < 65536 + 12288) {
    int t = idx - 65536;
    int j = t >> 8, k = t & 255;
    wTb48[t] = (j < 40) ? f2bf(x_proj_w[j * 256 + k]) : (unsigned short)0;
  } else if (idx < 65536 + 12288 + 32768) {
    int t = idx - (65536 + 12288);
    Woutb[t] = f2bf(out_proj_w[t]);
  } else if (idx < 65536 + 12288 + 32768 + 4096) {
    int t = idx - (65536 + 12288 + 32768);
    Aneg[t] = -__expf(A_log[t]);
  }
}

// ---------------- xz GEMM via bf16 MFMA -> d-major xT / zT ----------------
__global__ __launch_bounds__(256, 1) void gemm_xz_kernel(
    const float* __restrict__ x, const unsigned short* __restrict__ W2b,
    unsigned short* __restrict__ xT, unsigned short* __restrict__ zT) {
  __shared__ __align__(16) unsigned short At[128 * 128];
  __shared__ __align__(16) unsigned short Bt[256 * 128];
  int m0 = (blockIdx.x >> 1) * 128;
  int o0 = (blockIdx.x & 1) * 256;
  int b  = m0 >> 12;
  int l0 = m0 & 4095;
  int t = threadIdx.x;
  #pragma unroll
  for (int j = 0; j < 16; ++j) {
    int flat = t + j * 256;
    int cr = flat >> 5, lq = (flat & 31) << 2;
    float4 v = *reinterpret_cast<const float4*>(
        &x[((size_t)(b * 128 + cr)) * 4096 + l0 + lq]);
    float vv[4] = {v.x, v.y, v.z, v.w};
    #pragma unroll
    for (int e = 0; e < 4; ++e) {
      int l = lq + e;
      int g = (cr >> 3) ^ ((l & 7) << 1);
      At[l * 128 + g * 8 + (cr & 7)] = f2bf(vv[e]);
    }
  }
  #pragma unroll
  for (int j = 0; j < 16; ++j) {
    int flat = t + j * 256;
    int row = flat >> 4, gB = flat & 15;
    s16x8 v = *reinterpret_cast<const s16x8*>(&W2b[(size_t)(o0 + row) * 128 + gB * 8]);
    int g = gB ^ ((row & 7) << 1);
    *reinterpret_cast<s16x8*>(&Bt[row * 128 + g * 8]) = v;
  }
  __syncthreads();
  int ln = t & 63, wave = t >> 6;
  int wm = wave & 1, wn = wave >> 1;
  f32x4 acc[4][8] = {};
  #pragma unroll
  for (int ks = 0; ks < 4; ++ks) {
    int gk = ks * 4 + (ln >> 4);
    s16x8 a[4], bb[8];
    #pragma unroll
    for (int mi = 0; mi < 4; ++mi) {
      int lr = wm * 64 + mi * 16 + (ln & 15);
      a[mi] = *reinterpret_cast<const s16x8*>(&At[lr * 128 + (gk ^ ((lr & 7) << 1)) * 8]);
    }
    #pragma unroll
    for (int ni = 0; ni < 8; ++ni) {
      int orow = wn * 128 + ni * 16 + (ln & 15);
      bb[ni] = *reinterpret_cast<const s16x8*>(&Bt[orow * 128 + (gk ^ ((orow & 7) << 1)) * 8]);
    }
    #pragma unroll
    for (int mi = 0; mi < 4; ++mi)
      #pragma unroll
      for (int ni = 0; ni < 8; ++ni)
        acc[mi][ni] = __builtin_amdgcn_mfma_f32_16x16x32_bf16(a[mi], bb[ni], acc[mi][ni], 0, 0, 0);
  }
  // transposed write: lane holds 4 consecutive l for fixed o-col -> ushort4
  unsigned short* T = (o0 == 0) ? xT : zT;
  #pragma unroll
  for (int mi = 0; mi < 4; ++mi)
    #pragma unroll
    for (int ni = 0; ni < 8; ++ni) {
      int colg = wn * 128 + ni * 16 + (ln & 15);      // d within half
      int lrow = l0 + wm * 64 + mi * 16 + ((ln >> 4) << 2);
      ushort4 h4{f2bf(acc[mi][ni][0]), f2bf(acc[mi][ni][1]),
                 f2bf(acc[mi][ni][2]), f2bf(acc[mi][ni][3])};
      *reinterpret_cast<ushort4*>(&T[((size_t)(b * 256 + colg)) * 4096 + lrow]) = h4;
    }
}

// ---------------- conv4 + silu: thread=(d, 16 l), fully vectorized ----------------
__global__ __launch_bounds__(256) void conv_silu_kernel(
    const unsigned short* __restrict__ xT, const float* __restrict__ conv_w,
    const float* __restrict__ conv_b, unsigned short* __restrict__ xcT,
    unsigned short* __restrict__ xcb) {
  __shared__ unsigned short sxc[16][256];
  int blk = blockIdx.x;                 // 4 b x 256 chunks of 16 l
  int b = blk >> 8, ch = blk & 255;
  int l0 = ch * 16;
  int d = threadIdx.x;
  size_t rowbase = ((size_t)(b * 256 + d)) * 4096;
  // window [l0-8, l0+16): 3 x 16B (16B-aligned since l0 mult of 16)
  s16x8 w16[3];
  const s16x8* src = reinterpret_cast<const s16x8*>(&xT[rowbase + l0 - 8]);
  w16[0] = src[0]; w16[1] = src[1]; w16[2] = src[2];
  float wf[24];
  #pragma unroll
  for (int i = 0; i < 3; ++i)
    #pragma unroll
    for (int e = 0; e < 8; ++e)
      wf[i * 8 + e] = bfu((unsigned short)w16[i][e]);
  if (l0 == 0) { wf[5] = 0.f; wf[6] = 0.f; wf[7] = 0.f; }
  float w0 = conv_w[d * 4 + 0], w1 = conv_w[d * 4 + 1];
  float w2 = conv_w[d * 4 + 2], w3 = conv_w[d * 4 + 3];
  float cb = conv_b[d];
  unsigned short outv[16];
  #pragma unroll
  for (int r = 0; r < 16; ++r) {
    float acc = cb + w3 * wf[8 + r] + w2 * wf[7 + r] + w1 * wf[6 + r] + w0 * wf[5 + r];
    float s = acc * (1.f / (1.f + __expf(-acc)));
    unsigned short v = f2bf(s);
    outv[r] = v;
    sxc[r][d] = v;                       // conflict-free: consecutive d
  }
  #pragma unroll
  for (int i = 0; i < 2; ++i) {
    s16x8 v;
    #pragma unroll
    for (int e = 0; e < 8; ++e) v[e] = (short)outv[i * 8 + e];
    *reinterpret_cast<s16x8*>(&xcT[rowbase + l0 + i * 8]) = v;
  }
  __syncthreads();
  // flush l-major xcb: 16 l x 256 d / (8 per store) = 512 stores / 256 thr = 2
  #pragma unroll
  for (int it = 0; it < 2; ++it) {
    int idx = d + it * 256;
    int l = idx >> 5, ds8 = (idx & 31) * 8;
    s16x8 v = *reinterpret_cast<const s16x8*>(&sxc[l][ds8]);
    *reinterpret_cast<s16x8*>(&xcb[((size_t)(b * 4096 + l0 + l)) * 256 + ds8]) = v;
  }
}

// ---------------- x_dbl via bf16 MFMA: [16384 x 48] = xcb @ wTb48^T ----------------
__global__ __launch_bounds__(256) void xdbl_mfma_kernel(
    const unsigned short* __restrict__ xcb, const unsigned short* __restrict__ wTb48,
    float* __restrict__ xdbl48) {
  __shared__ __align__(16) unsigned short At[64 * 256];
  __shared__ __align__(16) unsigned short Bt[48 * 256];
  int m0 = blockIdx.x * 64;
  int t = threadIdx.x;
  #pragma unroll
  for (int it = 0; it < 8; ++it) {
    int f = t + it * 256;
    int row = f >> 5, g0 = f & 31;
    s16x8 v = *reinterpret_cast<const s16x8*>(&xcb[(size_t)(m0 + row) * 256 + g0 * 8]);
    int g = g0 ^ ((row & 7) << 1);
    *reinterpret_cast<s16x8*>(&At[row * 256 + g * 8]) = v;
  }
  #pragma unroll
  for (int it = 0; it < 6; ++it) {
    int f = t + it * 256;
    int row = f >> 5, g0 = f & 31;
    s16x8 v = *reinterpret_cast<const s16x8*>(&wTb48[(size_t)row * 256 + g0 * 8]);
    int g = g0 ^ ((row & 7) << 1);
    *reinterpret_cast<s16x8*>(&Bt[row * 256 + g * 8]) = v;
  }
  __syncthreads();
  int ln = t & 63, wm = t >> 6;
  f32x4 acc[3] = {};
  #pragma unroll
  for (int ks = 0; ks < 8; ++ks) {
    int gk = ks * 4 + (ln >> 4);
    int ar = wm * 16 + (ln & 15);
    s16x8 a = *reinterpret_cast<const s16x8*>(&At[ar * 256 + (gk ^ ((ar & 7) << 1)) * 8]);
    #pragma unroll
    for (int nt = 0; nt < 3; ++nt) {
      int br = nt * 16 + (ln & 15);
      s16x8 bb = *reinterpret_cast<const s16x8*>(&Bt[br * 256 + (gk ^ ((br & 7) << 1)) * 8]);
      acc[nt] = __builtin_amdgcn_mfma_f32_16x16x32_bf16(a, bb, acc[nt], 0, 0, 0);
    }
  }
  #pragma unroll
  for (int nt = 0; nt < 3; ++nt)
    #pragma unroll
    for (int r = 0; r < 4; ++r) {
      int row = m0 + wm * 16 + (ln >> 4) * 4 + r;
      xdbl48[(size_t)row * 48 + nt * 16 + (ln & 15)] = acc[nt][r];
    }
}

// ---------------- scan phase 1 ----------------
__global__ __launch_bounds__(256) void scan1_kernel(
    const unsigned short* __restrict__ xcT, const float* __restrict__ xdbl48,
    const float* __restrict__ dt_proj_w, const float* __restrict__ dt_proj_b,
    const float* __restrict__ Aneg,
    float* __restrict__ Ssum, float* __restrict__ chH) {
  __shared__ __align__(16) float lBC[CLEN][32];
  __shared__ __align__(16) float sdtr[CLEN][8];
  int blk = blockIdx.x;                // b*128 + c
  int b = blk >> 7, c = blk & 127;
  int bl0 = blk * CLEN;
  int tid = threadIdx.x;
  {
    int t0 = tid >> 3, q = (tid & 7) << 2;
    *reinterpret_cast<float4*>(&lBC[t0][q]) =
        *reinterpret_cast<const float4*>(&xdbl48[(size_t)(bl0 + t0) * 48 + 8 + q]);
    if (tid < 64) {
      int t1 = tid >> 1, q1 = (tid & 1) << 2;
      *reinterpret_cast<float4*>(&sdtr[t1][q1]) =
          *reinterpret_cast<const float4*>(&xdbl48[(size_t)(bl0 + t1) * 48 + q1]);
    }
  }
  int d = tid;
  float wrow[8];
  *reinterpret_cast<float4*>(&wrow[0]) = *reinterpret_cast<const float4*>(&dt_proj_w[d * 8]);
  *reinterpret_cast<float4*>(&wrow[4]) = *reinterpret_cast<const float4*>(&dt_proj_w[d * 8 + 4]);
  float bb = dt_proj_b[d];
  float An[16];
  #pragma unroll
  for (int q = 0; q < 4; ++q)
    *reinterpret_cast<float4*>(&An[q * 4]) =
        *reinterpret_cast<const float4*>(&Aneg[d * 16 + q * 4]);
  s16x8 xw[4];
  {
    const s16x8* src = reinterpret_cast<const s16x8*>(
        &xcT[((size_t)(b * 256 + d)) * 4096 + c * CLEN]);
    xw[0] = src[0]; xw[1] = src[1]; xw[2] = src[2]; xw[3] = src[3];
  }
  __syncthreads();
  float h[16] = {};
  float S = 0.f;
  #pragma unroll
  for (int t = 0; t < CLEN; ++t) {
    float a = bb;
    #pragma unroll
    for (int q = 0; q < 8; ++q) a += sdtr[t][q] * wrow[q];
    float dlv = fmaxf(a, 0.f) + __logf(1.f + __expf(-fabsf(a)));
    S += dlv;
    float dlx = dlv * bfu((unsigned short)xw[t >> 3][t & 7]);
    #pragma unroll
    for (int n = 0; n < 16; ++n)
      h[n] = __expf(dlv * An[n]) * h[n] + dlx * lBC[t][n];
  }
  int p = b * 256 + d;
  Ssum[c * 1024 + p] = S;
  size_t base = ((size_t)(c * 1024 + p)) * 16;
  #pragma unroll
  for (int q = 0; q < 4; ++q) {
    float4 v{h[q*4+0], h[q*4+1], h[q*4+2], h[q*4+3]};
    *reinterpret_cast<float4*>(&chH[base + q * 4]) = v;
  }
}

// ---------------- scan phase 2: chunk prefix (fp32, restrict) ----------------
__global__ void scan2_kernel(const float* __restrict__ Aneg,
                             const float* __restrict__ Ssum,
                             const float* __restrict__ chH,
                             float* __restrict__ chS) {
  int q = blockIdx.x * blockDim.x + threadIdx.x;  // 0..16383
  int p = q >> 4, n = q & 15;
  int d = p & 255;
  float An = Aneg[d * 16 + n];
  float h = 0.f;
  #pragma unroll 8
  for (int c = 0; c < NCHUNK; ++c) {
    size_t idx = ((size_t)(c * 1024 + p)) * 16 + n;
    float S = Ssum[c * 1024 + p];
    float hl = chH[idx];
    chS[idx] = h;
    h = __expf(An * S) * h + hl;
  }
}

// ---------------- scan phase 3: replay + y -> LDS transpose -> l-major y2b ----------------
__global__ __launch_bounds__(256) void scan3_kernel(
    const unsigned short* __restrict__ xcT, const unsigned short* __restrict__ zT,
    const float* __restrict__ xdbl48,
    const float* __restrict__ dt_proj_w, const float* __restrict__ dt_proj_b,
    const float* __restrict__ Aneg, const float* __restrict__ chS,
    const float* __restrict__ Dvec, unsigned short* __restrict__ y2b) {
  __shared__ __align__(16) float lBC[CLEN][32];
  __shared__ __align__(16) float sdtr[CLEN][8];
  __shared__ unsigned short sy[CLEN][256];
  int blk = blockIdx.x;
  int b = blk >> 7, c = blk & 127;
  int bl0 = blk * CLEN;
  int tid = threadIdx.x;
  {
    int t0 = tid >> 3, q = (tid & 7) << 2;
    *reinterpret_cast<float4*>(&lBC[t0][q]) =
        *reinterpret_cast<const float4*>(&xdbl48[(size_t)(bl0 + t0) * 48 + 8 + q]);
    if (tid < 64) {
      int t1 = tid >> 1, q1 = (tid & 1) << 2;
      *reinterpret_cast<float4*>(&sdtr[t1][q1]) =
          *reinterpret_cast<const float4*>(&xdbl48[(size_t)(bl0 + t1) * 48 + q1]);
    }
  }
  int d = tid;
  float wrow[8];
  *reinterpret_cast<float4*>(&wrow[0]) = *reinterpret_cast<const float4*>(&dt_proj_w[d * 8]);
  *reinterpret_cast<float4*>(&wrow[4]) = *reinterpret_cast<const float4*>(&dt_proj_w[d * 8 + 4]);
  float bb = dt_proj_b[d];
  float An[16];
  #pragma unroll
  for (int q = 0; q < 4; ++q)
    *reinterpret_cast<float4*>(&An[q * 4]) =
        *reinterpret_cast<const float4*>(&Aneg[d * 16 + q * 4]);
  int p = b * 256 + d;
  float h[16];
  {
    size_t base = ((size_t)(c * 1024 + p)) * 16;
    #pragma unroll
    for (int q = 0; q < 4; ++q) {
      float4 v = *reinterpret_cast<const float4*>(&chS[base + q * 4]);
      h[q*4+0] = v.x; h[q*4+1] = v.y; h[q*4+2] = v.z; h[q*4+3] = v.w;
    }
  }
  s16x8 xw[4], zw[4];
  {
    size_t rb = ((size_t)(b * 256 + d)) * 4096 + c * CLEN;
    const s16x8* sx = reinterpret_cast<const s16x8*>(&xcT[rb]);
    const s16x8* sz = reinterpret_cast<const s16x8*>(&zT[rb]);
    xw[0] = sx[0]; xw[1] = sx[1]; xw[2] = sx[2]; xw[3] = sx[3];
    zw[0] = sz[0]; zw[1] = sz[1]; zw[2] = sz[2]; zw[3] = sz[3];
  }
  float Dd = Dvec[d];
  __syncthreads();
  #pragma unroll
  for (int t = 0; t < CLEN; ++t) {
    float a = bb;
    #pragma unroll
    for (int q = 0; q < 8; ++q) a += sdtr[t][q] * wrow[q];
    float dlv = fmaxf(a, 0.f) + __logf(1.f + __expf(-fabsf(a)));
    float xval = bfu((unsigned short)xw[t >> 3][t & 7]);
    float dlx = dlv * xval;
    float y = 0.f;
    #pragma unroll
    for (int n = 0; n < 16; ++n) {
      h[n] = __expf(dlv * An[n]) * h[n] + dlx * lBC[t][n];
      y += h[n] * lBC[t][16 + n];
    }
    float z = bfu((unsigned short)zw[t >> 3][t & 7]);
    float sil = z * (1.f / (1.f + __expf(-z)));
    sy[t][d] = f2bf((y + xval * Dd) * sil);
  }
  __syncthreads();
  // flush l-major: 32 l x 256 d / 8 = 1024 stores / 256 thr = 4
  #pragma unroll
  for (int it = 0; it < 4; ++it) {
    int idx = tid + it * 256;
    int l = idx >> 5, ds8 = (idx & 31) * 8;
    s16x8 v = *reinterpret_cast<const s16x8*>(&sy[l][ds8]);
    *reinterpret_cast<s16x8*>(&y2b[((size_t)(bl0 + l)) * 256 + ds8]) = v;
  }
}

// ---------------- out GEMM via bf16 MFMA: out = Wout @ y2 + x ----------------
__global__ __launch_bounds__(256) void gemm_out_kernel(
    const unsigned short* __restrict__ y2b, const unsigned short* __restrict__ Woutb,
    const float* __restrict__ x, float* __restrict__ out) {
  __shared__ __align__(16) unsigned short At[64 * 256];
  __shared__ __align__(16) unsigned short Bt[128 * 256];
  int m0 = blockIdx.x * 64;
  int b = m0 >> 12, l0 = m0 & 4095;
  int t = threadIdx.x;
  #pragma unroll
  for (int it = 0; it < 8; ++it) {
    int f = t + it * 256;
    int row = f >> 5, g0 = f & 31;
    s16x8 v = *reinterpret_cast<const s16x8*>(&y2b[(size_t)(m0 + row) * 256 + g0 * 8]);
    int g = g0 ^ ((row & 7) << 1);
    *reinterpret_cast<s16x8*>(&At[row * 256 + g * 8]) = v;
  }
  #pragma unroll
  for (int it = 0; it < 16; ++it) {
    int f = t + it * 256;
    int row = f >> 5, g0 = f & 31;
    s16x8 v = *reinterpret_cast<const s16x8*>(&Woutb[(size_t)row * 256 + g0 * 8]);
    int g = g0 ^ ((row & 7) << 1);
    *reinterpret_cast<s16x8*>(&Bt[row * 256 + g * 8]) = v;
  }
  __syncthreads();
  int ln = t & 63, wm = t >> 6;
  f32x4 acc[8] = {};
  #pragma unroll
  for (int ks = 0; ks < 8; ++ks) {
    int gk = ks * 4 + (ln >> 4);
    int ar = wm * 16 + (ln & 15);
    s16x8 a = *reinterpret_cast<const s16x8*>(&At[ar * 256 + (gk ^ ((ar & 7) << 1)) * 8]);
    #pragma unroll
    for (int nt = 0; nt < 8; ++nt) {
      int br = nt * 16 + (ln & 15);
      s16x8 bb = *reinterpret_cast<const s16x8*>(&Bt[br * 256 + (gk ^ ((br & 7) << 1)) * 8]);
      acc[nt] = __builtin_amdgcn_mfma_f32_16x16x32_bf16(a, bb, acc[nt], 0, 0, 0);
    }
  }
  #pragma unroll
  for (int nt = 0; nt < 8; ++nt) {
    int cc = nt * 16 + (ln & 15);
    size_t base = ((size_t)(b * 128 + cc)) * 4096 + l0 + wm * 16 + ((ln >> 4) << 2);
    float4 xr = *reinterpret_cast<const float4*>(&x[base]);
    float4 o{acc[nt][0] + xr.x, acc[nt][1] + xr.y, acc[nt][2] + xr.z, acc[nt][3] + xr.w};
    *reinterpret_cast<float4*>(&out[base]) = o;
  }
}

extern "C" void kernel_launch(void* const* d_in, const int* in_sizes, int n_in,
                              void* d_out, int out_size, void* d_ws, size_t ws_size,
                              hipStream_t stream) {
  const float* x         = (const float*)d_in[0];
  const float* proj_w    = (const float*)d_in[1];
  const float* in_proj_w = (const float*)d_in[2];
  const float* conv_w    = (const float*)d_in[3];
  const float* conv_b    = (const float*)d_in[4];
  const float* x_proj_w  = (const float*)d_in[5];
  const float* dt_proj_w = (const float*)d_in[6];
  const float* dt_proj_b = (const float*)d_in[7];
  const float* A_log     = (const float*)d_in[8];
  const float* Dvec      = (const float*)d_in[9];
  const float* out_proj_w= (const float*)d_in[10];

  float* ws = (float*)d_ws;
  float*          Aneg   = ws;                                  // @0       (4096 f)
  unsigned short* W2b    = (unsigned short*)(ws + 4096);        // @4096    (32768 f)
  unsigned short* wTb48  = (unsigned short*)(ws + 36864);       // @36864   (6144 f)
  unsigned short* Woutb  = (unsigned short*)(ws + 43008);       // @43008   (16384 f)
  // 32 f pad @59392 gives 128B headroom before xT (conv reads l0-8 at d=0,b=0)
  unsigned short* xT     = (unsigned short*)(ws + 59424);       // @59424   (2097152 f)
  unsigned short* zT     = (unsigned short*)(ws + 2156576);     //          (2097152 f)
  unsigned short* xcT    = (unsigned short*)(ws + 4253728);     //          (2097152 f)
  unsigned short* xcb    = (unsigned short*)(ws + 6350880);     //          (2097152 f)
  float*          xdbl48 = ws + 8448032;                        //          (786432 f)
  float*          Ssum   = ws + 9234464;                        //          (131072 f)
  float*          chH    = ws + 9365536;                        //          (2097152 f)
  float*          chS    = ws + 11462688;                       //          (2097152 f)
  unsigned short* y2b    = (unsigned short*)(ws + 13559840);    //          (2097152 f)
  float* out = (float*)d_out;                                   // total ~63 MB

  prep_kernel<<<448, 256, 0, stream>>>(proj_w, in_proj_w, x_proj_w, out_proj_w, A_log,
                                       W2b, wTb48, Woutb, Aneg);
  gemm_xz_kernel<<<256, 256, 0, stream>>>(x, W2b, xT, zT);
  conv_silu_kernel<<<1024, 256, 0, stream>>>(xT, conv_w, conv_b, xcT, xcb);
  xdbl_mfma_kernel<<<256, 256, 0, stream>>>(xcb, wTb48, xdbl48);
  scan1_kernel<<<512, 256, 0, stream>>>(xcT, xdbl48, dt_proj_w, dt_proj_b, Aneg,
                                        Ssum, chH);
  scan2_kernel<<<64, 256, 0, stream>>>(Aneg, Ssum, chH, chS);
  scan3_kernel<<<512, 256, 0, stream>>>(xcT, zT, xdbl48, dt_proj_w, dt_proj_b, Aneg,
                                        chS, Dvec, y2b);
  gemm_out_kernel<<<256, 256, 0, stream>>>(y2b, Woutb, x, out);
}

// Round 10
// 178.020 us; speedup vs baseline: 1.0526x; 1.0342x over previous
//
#include <hip/hip_runtime.h>

// Mamba2D: B=4, C=128, H=W=64 (L=4096), D_INNER=256, D_STATE=16, DT_RANK=8, D_CONV=4
// 6-kernel pipeline; scan-side tensors d-major ([b][d][l]), GEMM-side l-major.
//  prep:     W2b=bf16(in_proj@proj); wTb48; Woutb; Aneg
//  gemm_xz:  bf16 MFMA, 64-l tile x BOTH o-halves (x read ONCE) -> d-major xT, zT
//  mid:      FUSED conv4+silu -> x_dbl MFMA (4-wave k-split + LDS reduce) -> scan1
//            outputs: xcT (d-major), xdbl48, Ssum, chH(fp32)
//  scan2:    chunk prefix (fp32)
//  scan3:    replay + y -> LDS transpose -> l-major bf16 y2b
//  gemm_out: bf16 MFMA, out = Wout @ y2 + x

#define NCHUNK 128
#define CLEN 32

using s16x8 = __attribute__((ext_vector_type(8))) short;
using f32x4 = __attribute__((ext_vector_type(4))) float;

__device__ inline unsigned short f2bf(float f) {
  unsigned u = __float_as_uint(f);
  u = u + 0x7FFF + ((u >> 16) & 1);
  return (unsigned short)(u >> 16);
}
__device__ inline float bfu(unsigned short v) {
  return __uint_as_float((unsigned)v << 16);
}

// ---------------- prep ----------------
__global__ void prep_kernel(const float* __restrict__ proj_w,
                            const float* __restrict__ in_proj_w,
                            const float* __restrict__ x_proj_w,
                            const float* __restrict__ out_proj_w,
                            const float* __restrict__ A_log,
                            unsigned short* __restrict__ W2b,
                            unsigned short* __restrict__ wTb48,
                            unsigned short* __restrict__ Woutb,
                            float* __restrict__ Aneg) {
  int idx = blockIdx.x * blockDim.x + threadIdx.x;
  if (idx < 65536) {
    int o = idx >> 7, c = idx & 127;
    float acc = 0.f;
    #pragma unroll 4
    for (int i = 0; i < 128; ++i)
      acc += in_proj_w[o * 128 + i] * proj_w[i * 128 + c];
    W2b[idx] = f2bf(acc);
  } else if (idx < 65536 + 12288) {
    int t = idx - 65536;
    int j = t >> 8, k = t & 255;
    wTb48[t] = (j < 40) ? f2bf(x_proj_w[j * 256 + k]) : (unsigned short)0;
  } else if (idx < 65536 + 12288 + 32768) {
    int t = idx - (65536 + 12288);
    Woutb[t] = f2bf(out_proj_w[t]);
  } else if (idx < 65536 + 12288 + 32768 + 4096) {
    int t = idx - (65536 + 12288 + 32768);
    Aneg[t] = -__expf(A_log[t]);
  }
}

// ---------------- xz GEMM: 64-l tile, both o-halves, x read once ----------------
__global__ __launch_bounds__(256) void gemm_xz_kernel(
    const float* __restrict__ x, const unsigned short* __restrict__ W2b,
    unsigned short* __restrict__ xT, unsigned short* __restrict__ zT) {
  __shared__ __align__(16) unsigned short At[64 * 128];   // 16 KB
  __shared__ __align__(16) unsigned short Bt[256 * 128];  // 64 KB
  int blk = blockIdx.x;              // 256: b*64 + ltile
  int b = blk >> 6;
  int l0 = (blk & 63) * 64;
  int t = threadIdx.x;
  // stage A once: x[b, 0:128, l0:l0+64] fp32 -> bf16 transposed + swizzled
  #pragma unroll
  for (int j = 0; j < 8; ++j) {
    int flat = t + j * 256;          // 0..2047
    int c = flat >> 4, lq = (flat & 15) << 2;
    float4 v = *reinterpret_cast<const float4*>(
        &x[((size_t)(b * 128 + c)) * 4096 + l0 + lq]);
    float vv[4] = {v.x, v.y, v.z, v.w};
    #pragma unroll
    for (int e = 0; e < 4; ++e) {
      int l = lq + e;
      int g = (c >> 3) ^ ((l & 7) << 1);
      At[l * 128 + g * 8 + (c & 7)] = f2bf(vv[e]);
    }
  }
  int ln = t & 63, w = t >> 6;
  for (int half = 0; half < 2; ++half) {
    int o0 = half * 256;
    __syncthreads();                 // protect Bt from prev iteration's readers
    #pragma unroll
    for (int j = 0; j < 16; ++j) {
      int flat = t + j * 256;
      int row = flat >> 4, gB = flat & 15;
      s16x8 v = *reinterpret_cast<const s16x8*>(&W2b[(size_t)(o0 + row) * 128 + gB * 8]);
      int g = gB ^ ((row & 7) << 1);
      *reinterpret_cast<s16x8*>(&Bt[row * 128 + g * 8]) = v;
    }
    __syncthreads();
    f32x4 acc[16] = {};
    #pragma unroll
    for (int ks = 0; ks < 4; ++ks) {
      int gk = ks * 4 + (ln >> 4);
      int ar = w * 16 + (ln & 15);
      s16x8 a = *reinterpret_cast<const s16x8*>(&At[ar * 128 + (gk ^ ((ar & 7) << 1)) * 8]);
      #pragma unroll
      for (int nt = 0; nt < 16; ++nt) {
        int br = nt * 16 + (ln & 15);
        s16x8 bb = *reinterpret_cast<const s16x8*>(&Bt[br * 128 + (gk ^ ((br & 7) << 1)) * 8]);
        acc[nt] = __builtin_amdgcn_mfma_f32_16x16x32_bf16(a, bb, acc[nt], 0, 0, 0);
      }
    }
    unsigned short* T = half ? zT : xT;
    #pragma unroll
    for (int nt = 0; nt < 16; ++nt) {
      int d = nt * 16 + (ln & 15);
      int lrow = l0 + w * 16 + ((ln >> 4) << 2);
      ushort4 h4{f2bf(acc[nt][0]), f2bf(acc[nt][1]), f2bf(acc[nt][2]), f2bf(acc[nt][3])};
      *reinterpret_cast<ushort4*>(&T[((size_t)(b * 256 + d)) * 4096 + lrow]) = h4;
    }
  }
}

// ---------------- mid: fused conv4+silu -> x_dbl MFMA -> scan1 ----------------
// block = one (b, chunk of 32 l). 512 blocks x 256 threads.
__global__ __launch_bounds__(256) void mid_kernel(
    const unsigned short* __restrict__ xT, const float* __restrict__ conv_w,
    const float* __restrict__ conv_b, const unsigned short* __restrict__ wTb48,
    const float* __restrict__ dt_proj_w, const float* __restrict__ dt_proj_b,
    const float* __restrict__ Aneg,
    unsigned short* __restrict__ xcT, float* __restrict__ xdbl48,
    float* __restrict__ Ssum, float* __restrict__ chH) {
  __shared__ __align__(16) unsigned short sxc[32 * 256];   // 16 KB, swizzled bf16
  __shared__ __align__(16) unsigned short sBt[48 * 256];   // 24 KB, swizzled bf16
  __shared__ __align__(16) float pxd[4 * 32 * 49];         // ~25 KB partials (pad 49)
  int blk = blockIdx.x;               // b*128 + c
  int b = blk >> 7, c = blk & 127;
  int l0 = c * CLEN;
  int bl0 = blk * CLEN;
  int d = threadIdx.x;
  // ---- conv: thread = d-column, 32 l + 3 history ----
  size_t rowbase = ((size_t)(b * 256 + d)) * 4096;
  float wf[40];
  {
    const s16x8* src = reinterpret_cast<const s16x8*>(&xT[rowbase + l0 - 8]);
    #pragma unroll
    for (int i = 0; i < 5; ++i) {
      s16x8 v = src[i];
      #pragma unroll
      for (int e = 0; e < 8; ++e) wf[i * 8 + e] = bfu((unsigned short)v[e]);
    }
    if (l0 == 0) { wf[5] = 0.f; wf[6] = 0.f; wf[7] = 0.f; }
  }
  float w0 = conv_w[d * 4 + 0], w1 = conv_w[d * 4 + 1];
  float w2 = conv_w[d * 4 + 2], w3 = conv_w[d * 4 + 3];
  float cb = conv_b[d];
  float xc[32];
  unsigned short xcb16[32];
  #pragma unroll
  for (int r = 0; r < 32; ++r) {
    float acc = cb + w3 * wf[8 + r] + w2 * wf[7 + r] + w1 * wf[6 + r] + w0 * wf[5 + r];
    float s = acc * (1.f / (1.f + __expf(-acc)));
    xc[r] = s;
    xcb16[r] = f2bf(s);
  }
  // write xcT (d-major, for scan3)
  #pragma unroll
  for (int i = 0; i < 4; ++i) {
    s16x8 v;
    #pragma unroll
    for (int e = 0; e < 8; ++e) v[e] = (short)xcb16[i * 8 + e];
    *reinterpret_cast<s16x8*>(&xcT[rowbase + l0 + i * 8]) = v;
  }
  // write sxc swizzled (A-operand layout for MFMA)
  #pragma unroll
  for (int l = 0; l < 32; ++l)
    sxc[l * 256 + (((d >> 3) ^ ((l & 7) << 1)) << 3) + (d & 7)] = xcb16[l];
  // stage wTb48 (B-operand, swizzled)
  #pragma unroll
  for (int it = 0; it < 6; ++it) {
    int f = d + it * 256;
    int row = f >> 5, g0 = f & 31;
    s16x8 v = *reinterpret_cast<const s16x8*>(&wTb48[(size_t)row * 256 + g0 * 8]);
    int g = g0 ^ ((row & 7) << 1);
    *reinterpret_cast<s16x8*>(&sBt[row * 256 + g * 8]) = v;
  }
  __syncthreads();
  // ---- x_dbl MFMA: M=32, N=48, K=256; wave w takes k-quarter ----
  {
    int ln = d & 63, w = d >> 6;
    f32x4 acc[2][3] = {};
    #pragma unroll
    for (int kk = 0; kk < 2; ++kk) {
      int ks = w * 2 + kk;
      int gk = ks * 4 + (ln >> 4);
      #pragma unroll
      for (int m = 0; m < 2; ++m) {
        int ar = m * 16 + (ln & 15);
        s16x8 a = *reinterpret_cast<const s16x8*>(&sxc[ar * 256 + (gk ^ ((ar & 7) << 1)) * 8]);
        #pragma unroll
        for (int nt = 0; nt < 3; ++nt) {
          int br = nt * 16 + (ln & 15);
          s16x8 bb = *reinterpret_cast<const s16x8*>(&sBt[br * 256 + (gk ^ ((br & 7) << 1)) * 8]);
          acc[m][nt] = __builtin_amdgcn_mfma_f32_16x16x32_bf16(a, bb, acc[m][nt], 0, 0, 0);
        }
      }
    }
    #pragma unroll
    for (int m = 0; m < 2; ++m)
      #pragma unroll
      for (int nt = 0; nt < 3; ++nt)
        #pragma unroll
        for (int r = 0; r < 4; ++r) {
          int row = m * 16 + (ln >> 4) * 4 + r;
          int col = nt * 16 + (ln & 15);
          pxd[(w * 32 + row) * 49 + col] = acc[m][nt][r];
        }
  }
  __syncthreads();
  // ---- reduce partials into pxd[0] and write xdbl48 ----
  #pragma unroll
  for (int it = 0; it < 6; ++it) {
    int idx = d + it * 256;          // 0..1535
    int l = idx / 48, j = idx - l * 48;
    float s = pxd[l * 49 + j] + pxd[(32 + l) * 49 + j] +
              pxd[(64 + l) * 49 + j] + pxd[(96 + l) * 49 + j];
    pxd[l * 49 + j] = s;
    xdbl48[(size_t)blk * 1536 + idx] = s;
  }
  __syncthreads();
  // ---- scan1: delta in-reg, h[16] recurrence ----
  float wrow[8];
  *reinterpret_cast<float4*>(&wrow[0]) = *reinterpret_cast<const float4*>(&dt_proj_w[d * 8]);
  *reinterpret_cast<float4*>(&wrow[4]) = *reinterpret_cast<const float4*>(&dt_proj_w[d * 8 + 4]);
  float bb = dt_proj_b[d];
  float An[16];
  #pragma unroll
  for (int q = 0; q < 4; ++q)
    *reinterpret_cast<float4*>(&An[q * 4]) =
        *reinterpret_cast<const float4*>(&Aneg[d * 16 + q * 4]);
  float h[16] = {};
  float S = 0.f;
  #pragma unroll
  for (int t = 0; t < CLEN; ++t) {
    float a = bb;
    #pragma unroll
    for (int q = 0; q < 8; ++q) a += pxd[t * 49 + q] * wrow[q];
    float dlv = fmaxf(a, 0.f) + __logf(1.f + __expf(-fabsf(a)));
    S += dlv;
    float dlx = dlv * xc[t];
    #pragma unroll
    for (int n = 0; n < 16; ++n)
      h[n] = __expf(dlv * An[n]) * h[n] + dlx * pxd[t * 49 + 8 + n];
  }
  int p = b * 256 + d;
  Ssum[c * 1024 + p] = S;
  size_t base = ((size_t)(c * 1024 + p)) * 16;
  #pragma unroll
  for (int q = 0; q < 4; ++q) {
    float4 v{h[q*4+0], h[q*4+1], h[q*4+2], h[q*4+3]};
    *reinterpret_cast<float4*>(&chH[base + q * 4]) = v;
  }
}

// ---------------- scan phase 2: chunk prefix ----------------
__global__ void scan2_kernel(const float* __restrict__ Aneg,
                             const float* __restrict__ Ssum,
                             const float* __restrict__ chH,
                             float* __restrict__ chS) {
  int q = blockIdx.x * blockDim.x + threadIdx.x;  // 0..16383
  int p = q >> 4, n = q & 15;
  int d = p & 255;
  float An = Aneg[d * 16 + n];
  float h = 0.f;
  #pragma unroll 8
  for (int c = 0; c < NCHUNK; ++c) {
    size_t idx = ((size_t)(c * 1024 + p)) * 16 + n;
    float S = Ssum[c * 1024 + p];
    float hl = chH[idx];
    chS[idx] = h;
    h = __expf(An * S) * h + hl;
  }
}

// ---------------- scan phase 3: replay + y -> LDS transpose -> l-major y2b ----------------
__global__ __launch_bounds__(256) void scan3_kernel(
    const unsigned short* __restrict__ xcT, const unsigned short* __restrict__ zT,
    const float* __restrict__ xdbl48,
    const float* __restrict__ dt_proj_w, const float* __restrict__ dt_proj_b,
    const float* __restrict__ Aneg, const float* __restrict__ chS,
    const float* __restrict__ Dvec, unsigned short* __restrict__ y2b) {
  __shared__ __align__(16) float lBC[CLEN][32];
  __shared__ __align__(16) float sdtr[CLEN][8];
  __shared__ unsigned short sy[CLEN][256];
  int blk = blockIdx.x;
  int b = blk >> 7, c = blk & 127;
  int bl0 = blk * CLEN;
  int tid = threadIdx.x;
  {
    int t0 = tid >> 3, q = (tid & 7) << 2;
    *reinterpret_cast<float4*>(&lBC[t0][q]) =
        *reinterpret_cast<const float4*>(&xdbl48[(size_t)(bl0 + t0) * 48 + 8 + q]);
    if (tid < 64) {
      int t1 = tid >> 1, q1 = (tid & 1) << 2;
      *reinterpret_cast<float4*>(&sdtr[t1][q1]) =
          *reinterpret_cast<const float4*>(&xdbl48[(size_t)(bl0 + t1) * 48 + q1]);
    }
  }
  int d = tid;
  float wrow[8];
  *reinterpret_cast<float4*>(&wrow[0]) = *reinterpret_cast<const float4*>(&dt_proj_w[d * 8]);
  *reinterpret_cast<float4*>(&wrow[4]) = *reinterpret_cast<const float4*>(&dt_proj_w[d * 8 + 4]);
  float bb = dt_proj_b[d];
  float An[16];
  #pragma unroll
  for (int q = 0; q < 4; ++q)
    *reinterpret_cast<float4*>(&An[q * 4]) =
        *reinterpret_cast<const float4*>(&Aneg[d * 16 + q * 4]);
  int p = b * 256 + d;
  float h[16];
  {
    size_t base = ((size_t)(c * 1024 + p)) * 16;
    #pragma unroll
    for (int q = 0; q < 4; ++q) {
      float4 v = *reinterpret_cast<const float4*>(&chS[base + q * 4]);
      h[q*4+0] = v.x; h[q*4+1] = v.y; h[q*4+2] = v.z; h[q*4+3] = v.w;
    }
  }
  s16x8 xw[4], zw[4];
  {
    size_t rb = ((size_t)(b * 256 + d)) * 4096 + c * CLEN;
    const s16x8* sx = reinterpret_cast<const s16x8*>(&xcT[rb]);
    const s16x8* sz = reinterpret_cast<const s16x8*>(&zT[rb]);
    xw[0] = sx[0]; xw[1] = sx[1]; xw[2] = sx[2]; xw[3] = sx[3];
    zw[0] = sz[0]; zw[1] = sz[1]; zw[2] = sz[2]; zw[3] = sz[3];
  }
  float Dd = Dvec[d];
  __syncthreads();
  #pragma unroll
  for (int t = 0; t < CLEN; ++t) {
    float a = bb;
    #pragma unroll
    for (int q = 0; q < 8; ++q) a += sdtr[t][q] * wrow[q];
    float dlv = fmaxf(a, 0.f) + __logf(1.f + __expf(-fabsf(a)));
    float xval = bfu((unsigned short)xw[t >> 3][t & 7]);
    float dlx = dlv * xval;
    float y = 0.f;
    #pragma unroll
    for (int n = 0; n < 16; ++n) {
      h[n] = __expf(dlv * An[n]) * h[n] + dlx * lBC[t][n];
      y += h[n] * lBC[t][16 + n];
    }
    float z = bfu((unsigned short)zw[t >> 3][t & 7]);
    float sil = z * (1.f / (1.f + __expf(-z)));
    sy[t][d] = f2bf((y + xval * Dd) * sil);
  }
  __syncthreads();
  #pragma unroll
  for (int it = 0; it < 4; ++it) {
    int idx = tid + it * 256;
    int l = idx >> 5, ds8 = (idx & 31) * 8;
    s16x8 v = *reinterpret_cast<const s16x8*>(&sy[l][ds8]);
    *reinterpret_cast<s16x8*>(&y2b[((size_t)(bl0 + l)) * 256 + ds8]) = v;
  }
}

// ---------------- out GEMM via bf16 MFMA: out = Wout @ y2 + x ----------------
__global__ __launch_bounds__(256) void gemm_out_kernel(
    const unsigned short* __restrict__ y2b, const unsigned short* __restrict__ Woutb,
    const float* __restrict__ x, float* __restrict__ out) {
  __shared__ __align__(16) unsigned short At[64 * 256];
  __shared__ __align__(16) unsigned short Bt[128 * 256];
  int m0 = blockIdx.x * 64;
  int b = m0 >> 12, l0 = m0 & 4095;
  int t = threadIdx.x;
  #pragma unroll
  for (int it = 0; it < 8; ++it) {
    int f = t + it * 256;
    int row = f >> 5, g0 = f & 31;
    s16x8 v = *reinterpret_cast<const s16x8*>(&y2b[(size_t)(m0 + row) * 256 + g0 * 8]);
    int g = g0 ^ ((row & 7) << 1);
    *reinterpret_cast<s16x8*>(&At[row * 256 + g * 8]) = v;
  }
  #pragma unroll
  for (int it = 0; it < 16; ++it) {
    int f = t + it * 256;
    int row = f >> 5, g0 = f & 31;
    s16x8 v = *reinterpret_cast<const s16x8*>(&Woutb[(size_t)row * 256 + g0 * 8]);
    int g = g0 ^ ((row & 7) << 1);
    *reinterpret_cast<s16x8*>(&Bt[row * 256 + g * 8]) = v;
  }
  __syncthreads();
  int ln = t & 63, wm = t >> 6;
  f32x4 acc[8] = {};
  #pragma unroll
  for (int ks = 0; ks < 8; ++ks) {
    int gk = ks * 4 + (ln >> 4);
    int ar = wm * 16 + (ln & 15);
    s16x8 a = *reinterpret_cast<const s16x8*>(&At[ar * 256 + (gk ^ ((ar & 7) << 1)) * 8]);
    #pragma unroll
    for (int nt = 0; nt < 8; ++nt) {
      int br = nt * 16 + (ln & 15);
      s16x8 bb = *reinterpret_cast<const s16x8*>(&Bt[br * 256 + (gk ^ ((br & 7) << 1)) * 8]);
      acc[nt] = __builtin_amdgcn_mfma_f32_16x16x32_bf16(a, bb, acc[nt], 0, 0, 0);
    }
  }
  #pragma unroll
  for (int nt = 0; nt < 8; ++nt) {
    int cc = nt * 16 + (ln & 15);
    size_t base = ((size_t)(b * 128 + cc)) * 4096 + l0 + wm * 16 + ((ln >> 4) << 2);
    float4 xr = *reinterpret_cast<const float4*>(&x[base]);
    float4 o{acc[nt][0] + xr.x, acc[nt][1] + xr.y, acc[nt][2] + xr.z, acc[nt][3] + xr.w};
    *reinterpret_cast<float4*>(&out[base]) = o;
  }
}

extern "C" void kernel_launch(void* const* d_in, const int* in_sizes, int n_in,
                              void* d_out, int out_size, void* d_ws, size_t ws_size,
                              hipStream_t stream) {
  const float* x         = (const float*)d_in[0];
  const float* proj_w    = (const float*)d_in[1];
  const float* in_proj_w = (const float*)d_in[2];
  const float* conv_w    = (const float*)d_in[3];
  const float* conv_b    = (const float*)d_in[4];
  const float* x_proj_w  = (const float*)d_in[5];
  const float* dt_proj_w = (const float*)d_in[6];
  const float* dt_proj_b = (const float*)d_in[7];
  const float* A_log     = (const float*)d_in[8];
  const float* Dvec      = (const float*)d_in[9];
  const float* out_proj_w= (const float*)d_in[10];

  float* ws = (float*)d_ws;
  float*          Aneg   = ws;                                  // 4096 f
  unsigned short* W2b    = (unsigned short*)(ws + 4096);        // 32768 f
  unsigned short* wTb48  = (unsigned short*)(ws + 36864);       // 6144 f
  unsigned short* Woutb  = (unsigned short*)(ws + 43008);       // 16384 f
  // 32-f pad before xT: mid reads xT[l0-8] at b=0,d=0,l0=0
  unsigned short* xT     = (unsigned short*)(ws + 59424);       // 2097152 f
  unsigned short* zT     = (unsigned short*)(ws + 2156576);     // 2097152 f
  unsigned short* xcT    = (unsigned short*)(ws + 4253728);     // 2097152 f
  float*          xdbl48 = ws + 6350880;                        // 786432 f
  float*          Ssum   = ws + 7137312;                        // 131072 f
  float*          chH    = ws + 7268384;                        // 2097152 f
  float*          chS    = ws + 9365536;                        // 2097152 f
  unsigned short* y2b    = (unsigned short*)(ws + 11462688);    // 2097152 f
  float* out = (float*)d_out;                                   // total ~54 MB

  prep_kernel<<<448, 256, 0, stream>>>(proj_w, in_proj_w, x_proj_w, out_proj_w, A_log,
                                       W2b, wTb48, Woutb, Aneg);
  gemm_xz_kernel<<<256, 256, 0, stream>>>(x, W2b, xT, zT);
  mid_kernel<<<512, 256, 0, stream>>>(xT, conv_w, conv_b, wTb48, dt_proj_w, dt_proj_b,
                                      Aneg, xcT, xdbl48, Ssum, chH);
  scan2_kernel<<<128, 128, 0, stream>>>(Aneg, Ssum, chH, chS);
  scan3_kernel<<<512, 256, 0, stream>>>(xcT, zT, xdbl48, dt_proj_w, dt_proj_b, Aneg,
                                        chS, Dvec, y2b);
  gemm_out_kernel<<<256, 256, 0, stream>>>(y2b, Woutb, x, out);
}